// Round 10
// baseline (178.600 us; speedup 1.0000x reference)
//
#include <hip/hip_runtime.h>
#include <math.h>

#define NB 10
#define H 512
#define W 512
#define OH 507
#define OW 507
#define GC 55           // output cols per group (lanes 1..55 emit)
#define NG 10           // col groups  (covers 550 >= 507)
#define SR 43           // output rows per strip
#define NS 12           // strips (12*43 = 516 >= 507)
// units = 32*NG*NS = 3840 waves; 4 units per 256-thread block -> 960 blocks
// = 3.75 blocks/CU, all resident (no LDS, VGPR<=128): barrier-free streaming.

__device__ __forceinline__ float f32mod10(float a) {
    float r = fmodf(a, 10.0f);
    if (r < 0.0f) r = __fadd_rn(r, 10.0f);
    return r;
}

struct ExactOut { int ib, it; float b_v, t_v; };
// bit-exact np-f32 reference chain (round-3 proven), from raw ring rows
__device__ __forceinline__ ExactOut exact_pixel(float rm, float rc, float rp) {
    float a00 = __shfl_up(rm, 1), a01 = rm, a02 = __shfl_down(rm, 1);
    float a10 = __shfl_up(rc, 1),           a12 = __shfl_down(rc, 1);
    float a20 = __shfl_up(rp, 1), a21 = rp, a22 = __shfl_down(rp, 1);
    float gxv = __fadd_rn(a00, -a02);
    gxv = __fadd_rn(gxv, __fmul_rn(2.0f, a10));
    gxv = __fadd_rn(gxv, -__fmul_rn(2.0f, a12));
    gxv = __fadd_rn(gxv, a20);
    gxv = __fadd_rn(gxv, -a22);
    float gyv = __fadd_rn(a00, __fmul_rn(2.0f, a01));
    gyv = __fadd_rn(gyv, a02);
    gyv = __fadd_rn(gyv, -a20);
    gyv = __fadd_rn(gyv, -__fmul_rn(2.0f, a21));
    gyv = __fadd_rn(gyv, -a22);
    float nrm = __fsqrt_rn(__fadd_rn(__fmul_rn(gxv, gxv), __fmul_rn(gyv, gyv)));
    float phf = (float)atan2((double)gxv, (double)gyv);
    float pe  = __fmul_rn(__fdiv_rn(phf, (float)3.14159265358979323846), 10.0f);
    float bfv = floorf(pe), tfv = ceilf(pe);
    float fm = f32mod10(pe), bm = f32mod10(bfv), tm = f32mod10(tfv);
    ExactOut e;
    e.t_v = __fmul_rn(nrm, __fsub_rn(1.0f, __fsub_rn(tm, fm)));
    e.b_v = __fmul_rn(nrm, __fsub_rn(1.0f, __fsub_rn(fm, bm)));
    e.ib = (((int)bfv % NB) + NB) % NB;
    e.it = (((int)tfv % NB) + NB) % NB;
    return e;
}

struct FastOut { float nrm, fm; bool exact; };
// fast path: gx = dm+2dc+dp, gy = sm-sp (regrouped conv; guard covers reorder)
__device__ __forceinline__ FastOut fast_pixel(float dm, float dc, float dp,
                                              float smv, float spv, bool valid) {
    float gxv = fmaf(2.0f, dc, dm) + dp;
    float gyv = smv - spv;
    float ay = fabsf(gxv), ax = fabsf(gyv);
    float hi = fmaxf(ax, ay), lo = fminf(ax, ay);
    float nrm = __builtin_amdgcn_sqrtf(fmaf(gxv, gxv, gyv * gyv));
    bool zero  = (hi == 0.0f);
    bool exact = (hi < 1e-30f) | (hi > 1e30f);
    float t  = lo * __builtin_amdgcn_rcpf(hi);
    bool red = t > 0.41421356f;
    float u  = red ? (t - 1.0f) * __builtin_amdgcn_rcpf(t + 1.0f) : t;
    float z  = u * u;
    float pl = ((8.05374449538e-2f * z - 1.38776856032e-1f) * z
                + 1.99777106478e-1f) * z - 3.33329491539e-1f;
    float a  = fmaf(u * z, pl, u);
    if (red) a += 0.78539816339744831f;
    if (ay > ax) a = 1.57079632679489662f - a;
    if (gyv < 0.0f) a = 3.14159265358979324f - a;
    float ph = (gxv < 0.0f) ? -a : a;
    float pint = ph * 3.18309886183790672f;
    exact = exact | (fabsf(pint - rintf(pint)) < 1e-4f);   // NaN-safe: stays true
    float fm = (pint < 0.0f) ? pint + 10.0f : pint;
    if (zero) { fm = 0.0f; exact = false; }                // nrm=0 -> contributes 0
    FastOut o;
    o.fm = fm;
    o.exact = exact && valid;
    o.nrm = (valid && !exact) ? nrm : 0.0f;
    return o;
}

// hat-identity scatter: ref's 2-bin deposit == nrm*max(0,1-|fm-k|) per bin,
// plus wrap strip (fm>9): bin0 gets (1+fm)*nrm  (verified == ref mod algebra)
__device__ __forceinline__ void hat_scatter(float R[NB], float v, float fm) {
    float w0 = (fm > 9.0f) ? (1.0f + fm) : fmaxf(0.0f, 1.0f - fm);
    R[0] = fmaf(v, w0, R[0]);
    #pragma unroll
    for (int k = 1; k < NB; ++k) {
        float w = fmaxf(0.0f, 1.0f - fabsf(fm - (float)k));
        R[k] = fmaf(v, w, R[k]);
    }
}

__device__ __forceinline__ void exact_scatter(float R[NB], const ExactOut& e,
                                              bool pred, float sgn) {
    #pragma unroll
    for (int k = 0; k < NB; ++k) {       // two separate adds, like rounds 3-8
        if (pred && e.ib == k) R[k] += sgn * e.b_v;
        if (pred && e.it == k) R[k] += sgn * e.t_v;
    }
}

__global__ __launch_bounds__(256, 4)
void hog_cols(const float* __restrict__ x, float* __restrict__ out) {
    const int lane = threadIdx.x & 63;
    const int u = blockIdx.x * 4 + (threadIdx.x >> 6);   // one wave = one unit
    const int n   = u / (NG * NS);
    const int rem = u - n * (NG * NS);
    const int s_  = rem / NG;
    const int g   = rem - s_ * NG;

    const int xcol = g * GC - 2 + lane;                  // input & hist col
    const bool col_ok = (unsigned)xcol < (unsigned)W;
    const float* __restrict__ xim = x + (size_t)n * (H * W);

    const int oy0 = s_ * SR;
    const int oyE = min(oy0 + SR, OH);
    const int hy_first = oy0 - 1;
    const int hy_last  = oyE + 5;

    float rw[10], sm[10], df[10], R[NB];
    #pragma unroll
    for (int k = 0; k < NB; ++k) R[k] = 0.0f;
    #pragma unroll
    for (int k = 0; k < 10; ++k) { rw[k] = 0.0f; sm[k] = 0.0f; df[k] = 0.0f; }

    auto LOAD = [&](int row) -> float {
        float v = 0.0f;
        if (col_ok && (unsigned)row < (unsigned)H) v = xim[row * W + xcol];
        return v;
    };
    auto PREP = [&](float raw, float& smv, float& dfv) {
        float l_ = __shfl_up(raw, 1);
        float r_ = __shfl_down(raw, 1);
        smv = (l_ + 2.0f * raw) + r_;
        dfv = l_ - r_;
    };

    rw[8] = LOAD(hy_first - 1); PREP(rw[8], sm[8], df[8]);
    rw[9] = LOAD(hy_first);     PREP(rw[9], sm[9], df[9]);
    float nextraw = LOAD(hy_first + 1);

    for (int hy = hy_first; hy <= hy_last; ++hy) {
        #pragma unroll
        for (int k = 0; k < 9; ++k) { rw[k] = rw[k+1]; sm[k] = sm[k+1]; df[k] = df[k+1]; }
        float raw = nextraw;
        nextraw = LOAD(hy + 2);                          // prefetch next row
        rw[9] = raw; PREP(raw, sm[9], df[9]);

        // ---- ADD: hist row hy (rows hy-1..hy+1 = ring 7..9) ----
        bool va = col_ok && ((unsigned)hy < (unsigned)H) && (lane >= 1 && lane <= 62);
        FastOut fa = fast_pixel(df[7], df[8], df[9], sm[7], sm[9], va);
        hat_scatter(R, fa.nrm, fa.fm);
        if (__any(fa.exact)) {
            ExactOut e = exact_pixel(rw[7], rw[8], rw[9]);
            exact_scatter(R, e, fa.exact, 1.0f);
        }

        if (hy >= hy_first + 7) {
            const int oy = hy - 6;                       // window [oy-1, oy+6] done
            const int oc = xcol + 1;
            const bool st = (lane >= 1 && lane <= GC) && (oc < OW);
            const float* dummy;
            (void)dummy;
            float* orow = out + ((size_t)(n * NB) * OH + oy) * OW;
            #pragma unroll
            for (int k = 0; k < NB; ++k) {
                float w = R[k];                          // horizontal 8-sum
                w += __shfl_down(w, 1);
                w += __shfl_down(w, 2);
                w += __shfl_down(w, 4);
                if (st) orow[oc] = w * (1.0f / 64.0f);
                orow += (size_t)OH * OW;
            }
            // ---- SUB: hist row hy-7 leaves window (rows = ring 0..2) ----
            const int hys = hy - 7;
            bool vs = col_ok && ((unsigned)hys < (unsigned)H) && (lane >= 1 && lane <= 62);
            FastOut fs = fast_pixel(df[0], df[1], df[2], sm[0], sm[2], vs);
            hat_scatter(R, -fs.nrm, fs.fm);
            if (__any(fs.exact)) {
                ExactOut e = exact_pixel(rw[0], rw[1], rw[2]);
                exact_scatter(R, e, fs.exact, -1.0f);
            }
        }
    }
}

extern "C" void kernel_launch(void* const* d_in, const int* in_sizes, int n_in,
                              void* d_out, int out_size, void* d_ws, size_t ws_size,
                              hipStream_t stream) {
    const float* x = (const float*)d_in[0];
    // d_in[1] is the fixed Sobel weight [2,1,3,3]; hard-coded in the kernel.
    float* out = (float*)d_out;
    const int units = 32 * NG * NS;                      // 3840
    hog_cols<<<dim3(units / 4), dim3(256), 0, stream>>>(x, out);
}

// Round 11
// 171.282 us; speedup vs baseline: 1.0427x; 1.0427x over previous
//
#include <hip/hip_runtime.h>
#include <math.h>

#define NB 10
#define H 512
#define W 512
#define OH 507
#define OW 507
#define TW 32           // output tile width
#define TH 16           // output tile height
#define HC (TW + 7)     // 39 hist cols  (ox0-1 .. ox0+TW+6)
#define HR (TH + 7)     // 23 hist rows
#define IC (TW + 9)     // 41 input cols (ox0-2 .. ox0+TW+7)
#define IR (TH + 9)     // 25 input rows
#define BD 512          // threads per block: 4 blocks/CU -> 32 waves/CU

// numpy float32 remainder (np.mod): fmod then sign-fix, each op exact IEEE f32.
__device__ __forceinline__ float f32mod10(float a) {
    float r = fmodf(a, 10.0f);
    if (r < 0.0f) r = __fadd_rn(r, 10.0f);
    return r;
}

__global__ __launch_bounds__(BD, 8)
void hog_fused(const float* __restrict__ x, float* __restrict__ out) {
    __shared__ __align__(16) float xin[IR][IC];      // 1025 f; reused as buf0 later
    __shared__ __align__(16) float hist[NB][HR][HC]; // 8970 f
    // total 9995 f = 39,980 B -> 4 blocks/CU, 512 thr each = 2048 thr/CU

    const int tid = threadIdx.x;
    const int ox0 = blockIdx.x * TW;
    const int oy0 = blockIdx.y * TH;
    const int n   = blockIdx.z;
    const float* __restrict__ xp = x + (size_t)n * (H * W);

    // ---- zero hist (vectorized) ----
    float* hflat = &hist[0][0][0];
    {
        float4* h4 = (float4*)hflat;                 // 8970 = 2242*4 + 2
        for (int i = tid; i < 2242; i += BD) h4[i] = make_float4(0.f, 0.f, 0.f, 0.f);
        if (tid < 2) hflat[8968 + tid] = 0.0f;
    }

    // ---- load input tile with halo (zero padded outside image) ----
    float* xflat = &xin[0][0];
    for (int i = tid; i < IR * IC; i += BD) {
        int r = i / IC, c = i % IC;
        int gy = oy0 - 2 + r, gx = ox0 - 2 + c;
        float v = 0.0f;
        if (gy >= 0 && gy < H && gx >= 0 && gx < W) v = xp[gy * W + gx];
        xflat[i] = v;
    }
    __syncthreads();

    // ---- Sobel + phase + 2-bin scatter into LDS hist ----
    // Ownership: exactly one thread per (hr,hc); hist pre-zeroed ->
    // scatter is PURE STORES (no read-modify-write LDS round-trips).
    for (int p = tid; p < HR * HC; p += BD) {
        int hr = p / HC, hc = p % HC;
        int hy = oy0 - 1 + hr, hx = ox0 - 1 + hc;
        if (hy < 0 || hy >= H || hx < 0 || hx >= W) continue;  // pool pad: zero
        float a00 = xin[hr][hc],     a01 = xin[hr][hc + 1],     a02 = xin[hr][hc + 2];
        float a10 = xin[hr + 1][hc],                            a12 = xin[hr + 1][hc + 2];
        float a20 = xin[hr + 2][hc], a21 = xin[hr + 2][hc + 1], a22 = xin[hr + 2][hc + 2];

        // exact numpy-order f32 conv (no contraction) — proven in round 3
        float gxv = __fadd_rn(a00, -a02);
        gxv = __fadd_rn(gxv, __fmul_rn(2.0f, a10));
        gxv = __fadd_rn(gxv, -__fmul_rn(2.0f, a12));
        gxv = __fadd_rn(gxv, a20);
        gxv = __fadd_rn(gxv, -a22);
        float gyv = __fadd_rn(a00, __fmul_rn(2.0f, a01));
        gyv = __fadd_rn(gyv, a02);
        gyv = __fadd_rn(gyv, -a20);
        gyv = __fadd_rn(gyv, -__fmul_rn(2.0f, a21));
        gyv = __fadd_rn(gyv, -a22);

        float ay_ = fabsf(gxv), ax_ = fabsf(gyv);
        float hi = fmaxf(ax_, ay_), lo = fminf(ax_, ay_);
        if (hi == 0.0f) continue;            // atan2(0,0)=0 -> contributes 0
        float nrm = __builtin_amdgcn_sqrtf(
            __fadd_rn(__fmul_rn(gxv, gxv), __fmul_rn(gyv, gyv)));

        // fast f32 atan2(gxv, gyv) * 10/pi, divide-free
        bool exact = (hi < 1e-30f) || (hi > 1e30f);
        float pint = 0.0f;
        if (!exact) {
            float t  = lo * __builtin_amdgcn_rcpf(hi);
            bool red = t > 0.41421356f;
            float u  = red ? (t - 1.0f) * __builtin_amdgcn_rcpf(t + 1.0f) : t;
            float z  = u * u;
            float pl = ((8.05374449538e-2f * z - 1.38776856032e-1f) * z
                        + 1.99777106478e-1f) * z - 3.33329491539e-1f;
            float a  = fmaf(u * z, pl, u);
            if (red) a += 0.78539816339744831f;
            if (ay_ > ax_) a = 1.57079632679489662f - a;
            if (gyv < 0.0f) a = 3.14159265358979324f - a;
            float ph = (gxv < 0.0f) ? -a : a;
            pint = ph * 3.18309886183790672f;
            if (fabsf(pint - rintf(pint)) < 1e-4f) exact = true;
        }

        float b_v, t_v;
        int ib, it;
        if (exact) {
            // bit-exact round-3 chain (matches np f32 reference)
            float phf = (float)atan2((double)gxv, (double)gyv);
            float pe  = __fmul_rn(__fdiv_rn(phf, (float)3.14159265358979323846), 10.0f);
            float bfv = floorf(pe), tfv = ceilf(pe);
            float fm = f32mod10(pe), bm = f32mod10(bfv), tm = f32mod10(tfv);
            t_v = __fmul_rn(nrm, __fsub_rn(1.0f, __fsub_rn(tm, fm)));
            b_v = __fmul_rn(nrm, __fsub_rn(1.0f, __fsub_rn(fm, bm)));
            ib = (((int)bfv % NB) + NB) % NB;
            it = (((int)tfv % NB) + NB) % NB;
        } else {
            // pint in (-10,10), >=1e-4 from any integer. Wrap strips
            // (t-index 0, tm=0) occur exactly when ib==9.
            float bfv  = floorf(pint);
            float frac = pint - bfv;
            float fm   = (pint < 0.0f) ? pint + 10.0f : pint;
            b_v = nrm * (1.0f - frac);
            int bi = (int)bfv;
            ib = (bi < 0) ? bi + 10 : bi;
            if (ib == 9) { it = 0;      t_v = nrm * (1.0f + fm); }
            else         { it = ib + 1; t_v = nrm * frac; }
        }
        // pure stores: cell owned by this thread, pre-zeroed background.
        // ib==it only possible on exact path (integer pe): ref does set
        // b_v then += t_v -> b_v + t_v.
        if (ib == it) {
            hist[ib][hr][hc] = __fadd_rn(b_v, t_v);
        } else {
            hist[ib][hr][hc] = b_v;
            hist[it][hr][hc] = t_v;
        }
    }
    __syncthreads();

    // ---- vertical 8-row sliding sum, IN PLACE (round-6 proven) ----
    float* buf0 = &xin[0][0];                          // [NB][HC] = 390 f
    for (int q = tid; q < NB * HC; q += BD) {
        int b = q / HC, hc = q % HC;
        float s = 0.0f;
        #pragma unroll
        for (int hr = 0; hr < 8; ++hr) s += hist[b][hr][hc];
        buf0[b * HC + hc] = s;
        #pragma unroll 4
        for (int i = 1; i < TH; ++i) {
            s += hist[b][i + 7][hc] - hist[b][i - 1][hc];
            hist[b][i - 1][hc] = s;                    // overwrite after last read
        }
    }
    __syncthreads();

    // ---- horizontal: sliding 8-sum, 4 outputs per unit (11 reads vs 32) ----
    // unit u: b = u>>7, i = (u>>3)&15, g4 = u&7 -> output cols ox0+4*g4 .. +3
    float* __restrict__ outn = out + (size_t)n * (NB * OH * OW);
    for (int u = tid; u < NB * TH * 8; u += BD) {
        int b  = u >> 7;
        int i  = (u >> 3) & 15;
        int g4 = u & 7;
        int oy = oy0 + i;
        if (oy >= OH) continue;
        const float* cs = (i == 0) ? (buf0 + b * HC) : &hist[b][i - 1][0];
        const float* p  = cs + 4 * g4;
        float w0 = p[0], w1 = p[1], w2 = p[2], w3 = p[3];
        float w4 = p[4], w5 = p[5], w6 = p[6], w7 = p[7];
        float o0 = ((w0 + w1) + (w2 + w3)) + ((w4 + w5) + (w6 + w7));
        float w8 = p[8], w9 = p[9], w10 = p[10];
        float o1 = o0 - w0 + w8;
        float o2 = o1 - w1 + w9;
        float o3 = o2 - w2 + w10;
        int oxg = ox0 + 4 * g4;
        float* po = outn + (size_t)(b * OH + oy) * OW + oxg;
        if (oxg + 3 < OW) {
            po[0] = o0 * (1.0f / 64.0f);
            po[1] = o1 * (1.0f / 64.0f);
            po[2] = o2 * (1.0f / 64.0f);
            po[3] = o3 * (1.0f / 64.0f);
        } else {
            if (oxg     < OW) po[0] = o0 * (1.0f / 64.0f);
            if (oxg + 1 < OW) po[1] = o1 * (1.0f / 64.0f);
            if (oxg + 2 < OW) po[2] = o2 * (1.0f / 64.0f);
        }
    }
}

extern "C" void kernel_launch(void* const* d_in, const int* in_sizes, int n_in,
                              void* d_out, int out_size, void* d_ws, size_t ws_size,
                              hipStream_t stream) {
    const float* x = (const float*)d_in[0];
    // d_in[1] is the fixed Sobel weight [2,1,3,3]; hard-coded in the kernel.
    float* out = (float*)d_out;
    dim3 grid((OW + TW - 1) / TW, (OH + TH - 1) / TH, 32);
    hog_fused<<<grid, dim3(BD), 0, stream>>>(x, out);
}